// Round 4
// baseline (530.606 us; speedup 1.0000x reference)
//
#include <hip/hip_runtime.h>
#include <hip/hip_bf16.h>
#include <math.h>

typedef _Float16 f16;
typedef f16 f16x8 __attribute__((ext_vector_type(8)));
typedef float f32x4 __attribute__((ext_vector_type(4)));

#define NBLK 512

// ============================================================================
// Grid-wide barrier: monotonic counter in workspace (zeroed each iteration by
// prep_video_kernel, which runs as the preceding dispatch on the stream).
// Release/acquire via __threadfence (agent-scope wbL2/invL2 on gfx950) makes
// cross-XCD writes visible. All NBLK blocks are co-resident by construction:
// 512 blocks, 48KB LDS (2x48=96 <= 160KB/CU), __launch_bounds__(256,2).
// ============================================================================
__device__ __forceinline__ void gridbar(unsigned* bar, unsigned target) {
  __syncthreads();
  if (threadIdx.x == 0) {
    __threadfence();  // release: flush this XCD's L2
    __hip_atomic_fetch_add(bar, 1u, __ATOMIC_RELAXED, __HIP_MEMORY_SCOPE_AGENT);
    while (__hip_atomic_load(bar, __ATOMIC_RELAXED, __HIP_MEMORY_SCOPE_AGENT) < target)
      __builtin_amdgcn_s_sleep(2);
    __threadfence();  // acquire: invalidate stale lines
  }
  __syncthreads();
}

// ============================================================================
// GEMM phase: C[M,N] = A[M,K](f16) @ Wt[N,K]^T(f16) + bias(f32), f16 store.
// Tile MT x 64, BK=64, 4 waves, dbuf ping-pong, ONE barrier per K-iter,
// register prefetch. LDS: MT=128 -> 48KB, MT=64 -> 32KB.
// bx = M-block (fast, %8 = XCD -> A shared within XCD), by = N-block.
// OUT: 1 = plain, 2 = + colsum atomics.
// ============================================================================
template<int MT, int RELU, int OUT>
__device__ __forceinline__ void gemm_phase(
    const f16* __restrict__ A, const f16* __restrict__ Wt,
    const float* __restrict__ bias, f16* __restrict__ Cout,
    const int ldc, const int K, float* __restrict__ colsum,
    const int bx, const int by, char* smem)
{
  constexpr int MI = MT / 32;
  f16* As = (f16*)smem;                 // [2][MT*64]
  f16* Bs = (f16*)(smem + MT * 256);    // [2][64*64]
  const int tid = threadIdx.x;
  const int wave = tid >> 6, lane = tid & 63;
  const int wm = (wave >> 1) * (MT / 2);
  const int wn = (wave & 1) * 32;
  const int m0 = bx * MT;
  const int n0 = by * 64;
  const int q = lane >> 4, r16 = lane & 15;

  const int rA0 = tid >> 3, gA0 = tid & 7;
  const f16* pA = A + (size_t)(m0 + rA0) * K + gA0 * 8;
  const f16* pB = Wt + (size_t)(n0 + rA0) * K + gA0 * 8;
  const int sbase = rA0 * 128 + ((gA0 ^ (rA0 & 7)) * 16);

  f32x4 acc[MI][2];
#pragma unroll
  for (int mi = 0; mi < MI; mi++)
#pragma unroll
    for (int ni = 0; ni < 2; ni++) acc[mi][ni] = (f32x4)0.f;

  f16x8 ar[MI], br[2];
#pragma unroll
  for (int j = 0; j < MI; j++) ar[j] = *(const f16x8*)(pA + (size_t)j * 32 * K);
#pragma unroll
  for (int j = 0; j < 2; j++) br[j] = *(const f16x8*)(pB + (size_t)j * 32 * K);

  const int iters = K >> 6;
  int p = 0;
  for (int it = 0; it < iters; it++) {
    f16* Asp = As + p * (MT * 64);
    f16* Bsp = Bs + p * (64 * 64);
#pragma unroll
    for (int j = 0; j < MI; j++)
      *(f16x8*)((char*)Asp + sbase + j * 4096) = ar[j];
#pragma unroll
    for (int j = 0; j < 2; j++)
      *(f16x8*)((char*)Bsp + sbase + j * 4096) = br[j];
    if (it + 1 < iters) {
      const int ko = (it + 1) << 6;
#pragma unroll
      for (int j = 0; j < MI; j++) ar[j] = *(const f16x8*)(pA + (size_t)j * 32 * K + ko);
#pragma unroll
      for (int j = 0; j < 2; j++) br[j] = *(const f16x8*)(pB + (size_t)j * 32 * K + ko);
    }
    __syncthreads();
#pragma unroll
    for (int h = 0; h < 2; h++) {
      const int kg = h * 4 + q;
      f16x8 af[MI], bf[2];
#pragma unroll
      for (int mi = 0; mi < MI; mi++) {
        const int row = wm + mi * 16 + r16;
        af[mi] = *(const f16x8*)((char*)Asp + row * 128 + ((kg ^ (row & 7)) * 16));
      }
#pragma unroll
      for (int ni = 0; ni < 2; ni++) {
        const int row = wn + ni * 16 + r16;
        bf[ni] = *(const f16x8*)((char*)Bsp + row * 128 + ((kg ^ (row & 7)) * 16));
      }
#pragma unroll
      for (int mi = 0; mi < MI; mi++)
#pragma unroll
        for (int ni = 0; ni < 2; ni++)
          acc[mi][ni] = __builtin_amdgcn_mfma_f32_16x16x32_f16(
              af[mi], bf[ni], acc[mi][ni], 0, 0, 0);
    }
    p ^= 1;
  }

#pragma unroll
  for (int ni = 0; ni < 2; ni++) {
    const int n = n0 + wn + ni * 16 + r16;
    const float bv = bias[n];
    float csum = 0.f;
#pragma unroll
    for (int mi = 0; mi < MI; mi++) {
#pragma unroll
      for (int rr = 0; rr < 4; rr++) {
        const int m = m0 + wm + mi * 16 + q * 4 + rr;
        float v = acc[mi][ni][rr] + bv;
        if (RELU) v = fmaxf(v, 0.f);
        if (OUT == 2) csum += v;
        Cout[(size_t)m * ldc + n] = (f16)v;
      }
    }
    if (OUT == 2) {
      csum += __shfl_xor(csum, 16);
      csum += __shfl_xor(csum, 32);
      if (q == 0) atomicAdd(&colsum[(m0 >> 10) * 256 + n], csum);
    }
  }
}

// ============================================================================
// ae-GEMM + bias + LayerNorm phase. 64 rows per block, N=256, K=128.
// B staged in two 128-col halves (keeps LDS at 16+32=48KB).
// ============================================================================
__device__ __forceinline__ void aeln_phase(
    const float* __restrict__ audio, const f16* __restrict__ wae_t,
    const float* __restrict__ b_ae, const float* __restrict__ ln_g,
    const float* __restrict__ ln_b, f16* __restrict__ a1,
    const int mb, char* smem)
{
  f16* As = (f16*)smem;              // [64][128] 16KB
  f16* Bs = (f16*)(smem + 16384);    // [128][128] 32KB
  const int tid = threadIdx.x;
  const int m0 = mb * 64;
  const int wave = tid >> 6, lane = tid & 63;
  const int q = lane >> 4, r16 = lane & 15;
  const int wm = wave * 16;
  // stage A [64][128] from f32 audio (10 real granules + 6 zero pad per row)
#pragma unroll
  for (int c = tid; c < 1024; c += 256) {
    const int row = c >> 4, g = c & 15;
    f16x8 val = (f16x8)(f16)0.f;
    if (g < 10) {
      const float* src = audio + (size_t)(m0 + row) * 80 + g * 8;
      const float4 u = *(const float4*)src;
      const float4 w = *(const float4*)(src + 4);
      val[0] = (f16)u.x; val[1] = (f16)u.y; val[2] = (f16)u.z; val[3] = (f16)u.w;
      val[4] = (f16)w.x; val[5] = (f16)w.y; val[6] = (f16)w.z; val[7] = (f16)w.w;
    }
    *(f16x8*)((char*)As + row * 256 + ((g ^ (row & 7)) * 16)) = val;
  }
  f32x4 acc[16];
#pragma unroll
  for (int a = 0; a < 16; a++) acc[a] = (f32x4)0.f;
#pragma unroll
  for (int h = 0; h < 2; h++) {
    if (h) __syncthreads();
#pragma unroll
    for (int c = tid; c < 2048; c += 256) {   // stage B half [128][128]
      const int row = c >> 4, g = c & 15;
      *(f16x8*)((char*)Bs + row * 256 + ((g ^ (row & 7)) * 16)) =
          *(const f16x8*)(wae_t + (size_t)(h * 128 + row) * 128 + g * 8);
    }
    __syncthreads();
#pragma unroll
    for (int kf = 0; kf < 4; kf++) {
      const int kg = kf * 4 + q;
      const int ar = wm + r16;
      const f16x8 af = *(const f16x8*)((char*)As + ar * 256 + ((kg ^ (ar & 7)) * 16));
#pragma unroll
      for (int nf = 0; nf < 8; nf++) {
        const int br = nf * 16 + r16;
        const f16x8 bf = *(const f16x8*)((char*)Bs + br * 256 + ((kg ^ (br & 7)) * 16));
        acc[h * 8 + nf] = __builtin_amdgcn_mfma_f32_16x16x32_f16(af, bf, acc[h * 8 + nf], 0, 0, 0);
      }
    }
  }
  // bias + per-row LN stats (rows q*4+rr, col = (a>>3)*128 + (a&7)*16 + r16)
  float rs[4] = {0.f, 0.f, 0.f, 0.f};
  float rq[4] = {0.f, 0.f, 0.f, 0.f};
#pragma unroll
  for (int a = 0; a < 16; a++) {
    const int col = (a >> 3) * 128 + (a & 7) * 16 + r16;
    const float bv = b_ae[col];
#pragma unroll
    for (int rr = 0; rr < 4; rr++) {
      const float v = acc[a][rr] + bv;
      acc[a][rr] = v;
      rs[rr] += v; rq[rr] += v * v;
    }
  }
#pragma unroll
  for (int off = 1; off < 16; off <<= 1) {
#pragma unroll
    for (int rr = 0; rr < 4; rr++) {
      rs[rr] += __shfl_xor(rs[rr], off);
      rq[rr] += __shfl_xor(rq[rr], off);
    }
  }
  float mu[4], ri[4];
#pragma unroll
  for (int rr = 0; rr < 4; rr++) {
    mu[rr] = rs[rr] * (1.0f / 256.0f);
    const float var = rq[rr] * (1.0f / 256.0f) - mu[rr] * mu[rr];
    ri[rr] = rsqrtf(var + 1e-5f);
  }
#pragma unroll
  for (int a = 0; a < 16; a++) {
    const int col = (a >> 3) * 128 + (a & 7) * 16 + r16;
    const float g = ln_g[col], bb = ln_b[col];
#pragma unroll
    for (int rr = 0; rr < 4; rr++) {
      const int row = m0 + wm + q * 4 + rr;
      a1[(size_t)row * 256 + col] = (f16)((acc[a][rr] - mu[rr]) * ri[rr] * g + bb);
    }
  }
}

// ============================================================================
// Heads GEMM + energy phase. bx = m-block (128), s = speaker (4).
// K=256 split into two staged halves of 128 (LDS 16+20=36KB).
// ============================================================================
__device__ __forceinline__ void heads_phase(
    const f16* __restrict__ A, const f16* __restrict__ Wt,
    const float* __restrict__ bias, float* __restrict__ specs,
    float* __restrict__ energy, const int bx, const int s, char* smem)
{
  f16* As = (f16*)smem;              // [64][128] 16KB
  f16* Bs = (f16*)(smem + 16384);    // [80][128] 20KB
  const int tid = threadIdx.x;
  const int m0 = bx * 64;
  const int wave = tid >> 6, lane = tid & 63;
  const int q = lane >> 4, r16 = lane & 15;
  const int wm = wave * 16;
  f32x4 acc[5];
#pragma unroll
  for (int nf = 0; nf < 5; nf++) acc[nf] = (f32x4)0.f;
#pragma unroll
  for (int kh = 0; kh < 2; kh++) {
    if (kh) __syncthreads();
#pragma unroll
    for (int c = tid; c < 1024; c += 256) {   // A K-half
      const int row = c >> 4, g = c & 15;
      *(f16x8*)((char*)As + row * 256 + ((g ^ (row & 7)) * 16)) =
          *(const f16x8*)(A + (size_t)(m0 + row) * 256 + kh * 128 + g * 8);
    }
#pragma unroll
    for (int c = tid; c < 1280; c += 256) {   // B K-half
      const int row = c >> 4, g = c & 15;
      *(f16x8*)((char*)Bs + row * 256 + ((g ^ (row & 7)) * 16)) =
          *(const f16x8*)(Wt + (size_t)(s * 80 + row) * 256 + kh * 128 + g * 8);
    }
    __syncthreads();
#pragma unroll
    for (int kf = 0; kf < 4; kf++) {
      const int kg = kf * 4 + q;
      const int ar = wm + r16;
      const f16x8 af = *(const f16x8*)((char*)As + ar * 256 + ((kg ^ (ar & 7)) * 16));
#pragma unroll
      for (int nf = 0; nf < 5; nf++) {
        const int br = nf * 16 + r16;
        const f16x8 bf = *(const f16x8*)((char*)Bs + br * 256 + ((kg ^ (br & 7)) * 16));
        acc[nf] = __builtin_amdgcn_mfma_f32_16x16x32_f16(af, bf, acc[nf], 0, 0, 0);
      }
    }
  }
  float bv[5];
#pragma unroll
  for (int nf = 0; nf < 5; nf++) bv[nf] = bias[s * 80 + nf * 16 + r16];
  float rs[4] = {0.f, 0.f, 0.f, 0.f};
#pragma unroll
  for (int rr = 0; rr < 4; rr++) {
    const int row = m0 + wm + q * 4 + rr;
    const int b_ = row >> 10, t_ = row & 1023;
    float* dst = specs + ((size_t)((b_ * 4 + s) * 1024 + t_)) * 80;
#pragma unroll
    for (int nf = 0; nf < 5; nf++) {
      const float v = acc[nf][rr] + bv[nf];
      rs[rr] += v;
      dst[nf * 16 + r16] = v;
    }
  }
#pragma unroll
  for (int off = 1; off < 16; off <<= 1) {
#pragma unroll
    for (int rr = 0; rr < 4; rr++) rs[rr] += __shfl_xor(rs[rr], off);
  }
  if (r16 == 0) {
#pragma unroll
    for (int rr = 0; rr < 4; rr++) {
      const int row = m0 + wm + q * 4 + rr;
      const int b_ = row >> 10, t_ = row & 1023;
      energy[((b_ * 4 + s) << 10) + t_] = rs[rr];
    }
  }
}

// ============================================================================
// Waveform helpers (threefry2x32 + fast erfinv)
// ============================================================================
__device__ __forceinline__ unsigned rotl32(unsigned x, int d) {
  return (x << d) | (x >> (32 - d));
}

__device__ __forceinline__ float erfinv_fast(float x) {
  const float t = (1.0f - x) * (1.0f + x);   // = 1 - x^2, no cancellation
  float w = -__logf(t);
  float p;
  if (w < 5.0f) {
    w = w - 2.5f;
    p = 2.81022636e-08f;
    p = fmaf(p, w, 3.43273939e-07f);
    p = fmaf(p, w, -3.5233877e-06f);
    p = fmaf(p, w, -4.39150654e-06f);
    p = fmaf(p, w, 0.00021858087f);
    p = fmaf(p, w, -0.00125372503f);
    p = fmaf(p, w, -0.00417768164f);
    p = fmaf(p, w, 0.246640727f);
    p = fmaf(p, w, 1.50140941f);
  } else {
    w = sqrtf(w) - 3.0f;
    p = -0.000200214257f;
    p = fmaf(p, w, 0.000100950558f);
    p = fmaf(p, w, 0.00134934322f);
    p = fmaf(p, w, -0.00367342844f);
    p = fmaf(p, w, 0.00573950773f);
    p = fmaf(p, w, -0.0076224613f);
    p = fmaf(p, w, 0.00943887047f);
    p = fmaf(p, w, 1.00167406f);
    p = fmaf(p, w, 2.83297682f);
  }
  return p * x;
}

__device__ __forceinline__ void waveform_unit(
    const float* __restrict__ energy, float* __restrict__ out, unsigned u)
{
  const unsigned base = (u * 256u + threadIdx.x) * 4u;
  const unsigned ks0 = 0u, ks1 = 1234u;
  const unsigned ks2 = 0x1BD11BDAu ^ ks0 ^ ks1;
  unsigned x0[4], x1[4];
#pragma unroll
  for (int j = 0; j < 4; j++) { x0[j] = ks0; x1[j] = base + (unsigned)j + ks1; }
#define TFR(r)                                                     \
  _Pragma("unroll") for (int j = 0; j < 4; j++) {                  \
    x0[j] += x1[j]; x1[j] = rotl32(x1[j], r); x1[j] ^= x0[j];      \
  }
#define TFK(ka, kb)                                                \
  _Pragma("unroll") for (int j = 0; j < 4; j++) {                  \
    x0[j] += (ka); x1[j] += (kb);                                  \
  }
  TFR(13) TFR(15) TFR(26) TFR(6)  TFK(ks1, ks2 + 1u)
  TFR(17) TFR(29) TFR(16) TFR(24) TFK(ks2, ks0 + 2u)
  TFR(13) TFR(15) TFR(26) TFR(6)  TFK(ks0, ks1 + 3u)
  TFR(17) TFR(29) TFR(16) TFR(24) TFK(ks1, ks2 + 4u)
  TFR(13) TFR(15) TFR(26) TFR(6)  TFK(ks2, ks0 + 5u)
#undef TFR
#undef TFK
  const unsigned i0 = base % 163840u;
  const unsigned bs = base / 163840u;
  const float* e = energy + (size_t)bs * 1024;
  float4 o;
#pragma unroll
  for (int j = 0; j < 4; j++) {
    const unsigned bits = x0[j] ^ x1[j];
    const float f = __uint_as_float((bits >> 9) | 0x3f800000u) - 1.0f;
    const float minv = -0.99999994f;
    const float uu = fmaxf(minv, fmaf(f, 2.0f, minv));
    const float noise = 1.41421354f * erfinv_fast(uu) * 0.1f;
    float pos = ((float)(i0 + j) + 0.5f) * 0.00625f - 0.5f;
    pos = fminf(fmaxf(pos, 0.0f), 1023.0f);
    const int lo = (int)floorf(pos);
    int hi = lo + 1; if (hi > 1023) hi = 1023;
    const float w = pos - (float)lo;
    const float ev = e[lo] * (1.0f - w) + e[hi] * w;
    ((float*)&o)[j] = noise * fmaf(ev, 0.5f, 0.5f);
  }
  *(float4*)(out + base) = o;
}

// ============================================================================
// Persistent mega-kernel: phases A..G separated by grid barriers.
// 512 blocks x 256 threads, 48KB LDS, 2 blocks/CU -> all co-resident.
// ============================================================================
__global__ __launch_bounds__(256, 2) void mega_kernel(
    const float* __restrict__ Sg, const float* __restrict__ conv_w,
    const float* __restrict__ conv_b, const float* __restrict__ w_vfc,
    const float* __restrict__ b_vfc, float* __restrict__ v256,
    const float* __restrict__ audio, const f16* __restrict__ wae_t,
    const float* __restrict__ b_ae, const float* __restrict__ ln_g,
    const float* __restrict__ ln_b, f16* __restrict__ a1,
    const f16* __restrict__ wa1_t, const float* __restrict__ b_a1,
    const f16* __restrict__ wa2_t, const float* __restrict__ b_a2,
    const f16* __restrict__ wf1_t, const float* __restrict__ b_f1,
    const f16* __restrict__ wf2_t, const float* __restrict__ b_f2,
    f16* __restrict__ h16, f16* __restrict__ fbuf16,
    const f16* __restrict__ wh_t, const float* __restrict__ bp,
    float* __restrict__ out_specs, float* __restrict__ energy,
    float* __restrict__ out_wave, float* __restrict__ colsum,
    const float* __restrict__ w_spk, const float* __restrict__ b_spk,
    float* __restrict__ out_logits, unsigned* __restrict__ bar)
{
  __shared__ __align__(16) char smem[49152];
  const int b = blockIdx.x;
  const int tid = threadIdx.x;

  // ---- phase A: vpool+FC (blocks 0-255) | ae-GEMM+LN (blocks 256-383) ----
  if (b < 256) {
    float* vp = (float*)smem;
    if (tid < 64) {
      float a = 0.f;
      const float* sgp = Sg + (size_t)b * 147;
#pragma unroll 7
      for (int k = 0; k < 147; k++) a = fmaf(conv_w[tid * 147 + k], sgp[k], a);
      vp[tid] = conv_b[tid] + a * (1.0f / 3136.0f);
    }
    __syncthreads();
    float a = 0.f;
#pragma unroll
    for (int k = 0; k < 64; k++) a = fmaf(vp[k], w_vfc[k * 256 + tid], a);
    v256[(size_t)b * 256 + tid] = a + b_vfc[tid];
  } else if (b < 384) {
    aeln_phase(audio, wae_t, b_ae, ln_g, ln_b, a1, b - 256, smem);
  }
  gridbar(bar, NBLK);

  // ---- phase B: h16 = relu(a1 @ wa1 + b_a1)   [M8192 N512 K256] ----
  gemm_phase<128, 1, 1>(a1, wa1_t, b_a1, h16, 512, 256, nullptr, b & 63, b >> 6, smem);
  gridbar(bar, 2 * NBLK);

  // ---- phase C: fbuf[:, :256] = h16 @ wa2 + b_a2 ; interp -> [:,256:] ----
  gemm_phase<64, 0, 1>(h16, wa2_t, b_a2, fbuf16, 512, 512, nullptr, b & 127, b >> 7, smem);
  if (b < 128) {
    const int base = b * 16384 + tid;
#pragma unroll 4
    for (int i = 0; i < 64; i++) {
      const int idx = base + i * 256;
      const int c = idx & 255;
      const int t = (idx >> 8) & 1023;
      const int bb = idx >> 18;
      float pos = ((float)t + 0.5f) * 0.03125f - 0.5f;
      pos = fminf(fmaxf(pos, 0.0f), 31.0f);
      const int lo = (int)floorf(pos);
      int hi = lo + 1; if (hi > 31) hi = 31;
      const float w = pos - (float)lo;
      const float vl = v256[(size_t)(bb * 32 + lo) * 256 + c];
      const float vh = v256[(size_t)(bb * 32 + hi) * 256 + c];
      fbuf16[(size_t)(bb * 1024 + t) * 512 + 256 + c] = (f16)(vl * (1.0f - w) + vh * w);
    }
  }
  gridbar(bar, 3 * NBLK);

  // ---- phase D: h16 = relu(fbuf @ wf1 + b_f1)  [M8192 N512 K512] ----
  gemm_phase<128, 1, 1>(fbuf16, wf1_t, b_f1, h16, 512, 512, nullptr, b & 63, b >> 6, smem);
  gridbar(bar, 4 * NBLK);

  // ---- phase E: a1 = h16 @ wf2 + b_f2 (+ colsum) [M8192 N256 K512] ----
  gemm_phase<64, 0, 2>(h16, wf2_t, b_f2, a1, 256, 512, colsum, b & 127, b >> 7, smem);
  gridbar(bar, 5 * NBLK);

  // ---- phase F: heads -> specs [B,S,T,80] + energy ----
  heads_phase(a1, wh_t, bp, out_specs, energy, b & 127, b >> 7, smem);
  gridbar(bar, 6 * NBLK);

  // ---- phase G: waveforms (10 units/block) + speaker logits ----
  for (int i = 0; i < 10; i++)
    waveform_unit(energy, out_wave, (unsigned)b + (unsigned)i * 512u);
  if (b == 0 && tid < 32) {
    const int bb = tid >> 2, s = tid & 3;
    const float* cs = colsum + bb * 256;
    float a = 0.f;
#pragma unroll 8
    for (int d = 0; d < 256; d++)
      a = fmaf(cs[d] * (1.0f / 1024.0f), w_spk[d * 4 + s], a);
    out_logits[bb * 4 + s] = a + b_spk[s];
  }
}

// ============================================================================
// Merged: video conv7x7 tap-reduction (blocks [0,768)) + weight-transpose
// prep (blocks [768, 3786)). Also zeroes colsum AND the grid-barrier counter.
// ============================================================================
__global__ __launch_bounds__(256) void prep_video_kernel(
    const float* __restrict__ video, float* __restrict__ Sg,
    const float* __restrict__ w_ae, const float* __restrict__ w_a1,
    const float* __restrict__ w_a2, const float* __restrict__ w_f1,
    const float* __restrict__ w_f2, const float* __restrict__ heads_w,
    const float* __restrict__ heads_b,
    f16* __restrict__ wae_t, f16* __restrict__ wa1_t,
    f16* __restrict__ wa2_t, f16* __restrict__ wf1_t, f16* __restrict__ wf2_t,
    f16* __restrict__ wh_t, float* __restrict__ bp, float* __restrict__ colsum)
{
  if (blockIdx.x < 768) {
    const int img = blockIdx.x;
    const float* p = video + (size_t)img * 12544;
    __shared__ float rowS[2][112];
    __shared__ float c0s[112], c1s[112], c109s[112], c110s[112], c111s[112];
    __shared__ float base[14];
    __shared__ float sE[7], sO[7];
    const int t = threadIdx.x;
    if (t < 224) {
      const int r = t >> 1;
      const int par = t & 1;
      const float* rp = p + r * 112 + par;
      float s = 0.f;
#pragma unroll
      for (int i = 0; i < 56; i++) s += rp[2 * i];
      rowS[par][r] = s;
      if (par == 0) { c0s[r] = rp[0]; c110s[r] = rp[110]; }
      else { c1s[r] = rp[0]; c109s[r] = rp[108]; c111s[r] = rp[110]; }
    }
    __syncthreads();
    if (t < 14) {
      const int arr = t >> 1;
      const int rp = t & 1;
      const float* src = (arr == 0) ? rowS[0] : (arr == 1) ? rowS[1] :
                         (arr == 2) ? c0s : (arr == 3) ? c1s :
                         (arr == 4) ? c109s : (arr == 5) ? c110s : c111s;
      float s = 0.f;
      for (int r = rp; r < 112; r += 2) s += src[r];
      base[t] = s;
    }
    __syncthreads();
    if (t < 7) {
      float se, so;
      switch (t) {
        case 0: se = base[2] - base[8] - base[12]; so = base[3] - base[9] - base[13]; break;
        case 1: se = base[0] - base[10];           so = base[1] - base[11];           break;
        case 2: se = base[2] - base[12];           so = base[3] - base[13];           break;
        case 3: se = base[0];                      so = base[1];                      break;
        case 4: se = base[2];                      so = base[3];                      break;
        case 5: se = base[0] - base[4];            so = base[1] - base[5];            break;
        default: se = base[2] - base[6];           so = base[3] - base[7];            break;
      }
      sE[t] = se; sO[t] = so;
    }
    __syncthreads();
    if (t < 49) {
      const int kh = t / 7, kw = t % 7;
      auto ccol = [&](int r) -> float {
        switch (kw) {
          case 0: return rowS[1][r] - c109s[r] - c111s[r];
          case 1: return rowS[0][r] - c110s[r];
          case 2: return rowS[1][r] - c111s[r];
          case 3: return rowS[0][r];
          case 4: return rowS[1][r];
          case 5: return rowS[0][r] - c0s[r];
          default: return rowS[1][r] - c1s[r];
        }
      };
      float v;
      switch (kh) {
        case 0: v = sO[kw] - ccol(109) - ccol(111); break;
        case 1: v = sE[kw] - ccol(110);             break;
        case 2: v = sO[kw] - ccol(111);             break;
        case 3: v = sE[kw];                         break;
        case 4: v = sO[kw];                         break;
        case 5: v = sE[kw] - ccol(0);               break;
        default: v = sO[kw] - ccol(1);              break;
      }
      Sg[(size_t)img * 49 + t] = v;
    }
    return;
  }
  int idx = (blockIdx.x - 768) * 256 + threadIdx.x;
  if (idx < 32768) {    // wae_t [256][128] (K padded 80->128)
    const int n = idx >> 7, k = idx & 127;
    wae_t[idx] = (f16)(k < 80 ? w_ae[k * 256 + n] : 0.f);
    return;
  }
  idx -= 32768;
  if (idx < 131072) { const int n = idx >> 8, k = idx & 255; wa1_t[idx] = (f16)w_a1[k * 512 + n]; return; }
  idx -= 131072;
  if (idx < 131072) { const int n = idx >> 9, k = idx & 511; wa2_t[idx] = (f16)w_a2[k * 256 + n]; return; }
  idx -= 131072;
  if (idx < 262144) { const int n = idx >> 9, k = idx & 511; wf1_t[idx] = (f16)w_f1[k * 512 + n]; return; }
  idx -= 262144;
  if (idx < 131072) { const int n = idx >> 9, k = idx & 511; wf2_t[idx] = (f16)w_f2[k * 256 + n]; return; }
  idx -= 131072;
  if (idx < 81920) {    // wh_t [320][256]
    const int n = idx >> 8, d = idx & 255;
    const int s = n / 80, o = n - s * 80;
    wh_t[idx] = (f16)heads_w[(size_t)(s * 256 + d) * 80 + o];
    return;
  }
  idx -= 81920;
  if (idx < 320) { bp[idx] = heads_b[idx]; return; }
  idx -= 320;
  if (idx < 2064) colsum[idx] = 0.f;   // colsum[2048] + barrier counter slots
}

// ============================================================================
extern "C" void kernel_launch(void* const* d_in, const int* in_sizes, int n_in,
                              void* d_out, int out_size, void* d_ws, size_t ws_size,
                              hipStream_t stream)
{
  (void)in_sizes; (void)n_in; (void)out_size; (void)ws_size;
  const float* audio   = (const float*)d_in[0];
  const float* video   = (const float*)d_in[1];
  const float* w_ae    = (const float*)d_in[2];
  const float* b_ae    = (const float*)d_in[3];
  const float* ln_g    = (const float*)d_in[4];
  const float* ln_b    = (const float*)d_in[5];
  const float* w_a1    = (const float*)d_in[6];
  const float* b_a1    = (const float*)d_in[7];
  const float* w_a2    = (const float*)d_in[8];
  const float* b_a2    = (const float*)d_in[9];
  const float* conv_w  = (const float*)d_in[10];
  const float* conv_b  = (const float*)d_in[11];
  const float* w_vfc   = (const float*)d_in[12];
  const float* b_vfc   = (const float*)d_in[13];
  const float* w_f1    = (const float*)d_in[14];
  const float* b_f1    = (const float*)d_in[15];
  const float* w_f2    = (const float*)d_in[16];
  const float* b_f2    = (const float*)d_in[17];
  const float* heads_w = (const float*)d_in[18];
  const float* heads_b = (const float*)d_in[19];
  const float* w_spk   = (const float*)d_in[20];
  const float* b_spk   = (const float*)d_in[21];

  float* ws = (float*)d_ws;
  float*    colsum = ws + 2097152;              // 2048 (+16 barrier slots)
  unsigned* bar    = (unsigned*)(ws + 2099200); // 16 slots, zeroed by prep
  float*    Sg     = ws + 2099264;              // 37,632
  float*    v256   = ws + 2136896;              // 65,536
  float*    energy = ws + 2202432;              // 32,768
  float*    bp     = ws + 2235200;              // 320
  f16* fh = (f16*)(ws + 2235584);
  f16* a1     = fh;                   // 2,097,152 f16
  f16* h16    = a1 + 2097152;         // 4,194,304
  f16* fbuf16 = h16 + 4194304;        // 4,194,304
  f16* wae_t  = fbuf16 + 4194304;     //    32,768
  f16* wa1_t  = wae_t + 32768;        //   131,072
  f16* wa2_t  = wa1_t + 131072;       //   131,072
  f16* wf1_t  = wa2_t + 131072;       //   262,144
  f16* wf2_t  = wf1_t + 262144;       //   131,072
  f16* wh_t   = wf2_t + 131072;       //    81,920

  float* out_wave   = (float*)d_out;           // 5,242,880
  float* out_specs  = out_wave + 5242880;      // 2,621,440
  float* out_logits = out_specs + 2621440;     // 32

  // 1. video tap-reduce + weight transposes + colsum/barrier zero
  prep_video_kernel<<<3786, 256, 0, stream>>>(video, Sg, w_ae, w_a1, w_a2,
                                              w_f1, w_f2, heads_w, heads_b,
                                              wae_t, wa1_t, wa2_t, wf1_t,
                                              wf2_t, wh_t, bp, colsum);
  // 2. persistent fused pipeline (phases A..G with grid barriers)
  mega_kernel<<<NBLK, 256, 0, stream>>>(
      Sg, conv_w, conv_b, w_vfc, b_vfc, v256,
      audio, wae_t, b_ae, ln_g, ln_b, a1,
      wa1_t, b_a1, wa2_t, b_a2, wf1_t, b_f1, wf2_t, b_f2,
      h16, fbuf16, wh_t, bp, out_specs, energy,
      out_wave, colsum, w_spk, b_spk, out_logits, bar);
}

// Round 5
// 216.481 us; speedup vs baseline: 2.4510x; 2.4510x over previous
//
#include <hip/hip_runtime.h>
#include <hip/hip_bf16.h>
#include <math.h>

typedef _Float16 f16;
typedef f16 f16x8 __attribute__((ext_vector_type(8)));
typedef f16 f16x4 __attribute__((ext_vector_type(4)));
typedef float f32x4 __attribute__((ext_vector_type(4)));

// ============================================================================
// fp16 MFMA GEMM: C[M,N] = A[M,K](f16) @ Wt[N,K]^T(f16) + bias(f32)
// Tile MT(M) x 64(N), MT in {64,128}. BK=64, 256 threads = 4 waves,
// wave tile (MT/2) x 32. Double-buffered LDS ping-pong, ONE barrier per
// K-iter, register prefetch.
// GRID IS TRANSPOSED: blockIdx.x = M-block, blockIdx.y = N-block.
// gridDim.x is a multiple of 8 -> all N-blocks sharing an A-tile land on
// the SAME XCD (bid = x + gridDim.x*y, gridDim.x % 8 == 0) -> A is fetched
// once per XCD instead of 8x.
// OUT: 1 = f16 store; 2 = f16 store + colsum atomics (speaker).
// XTRA: blockIdx.y == 4 runs the video temporal-interp (v256 -> fbuf cols
//       256..511) instead of GEMM work; colsum param carries v256.
// ============================================================================
template<int MT, int RELU, int OUT, int XTRA = 0>
__global__ __launch_bounds__(256) void hgemm(
    const f16* __restrict__ A, const f16* __restrict__ Wt,
    const float* __restrict__ bias,
    void* __restrict__ Cout, int ldc, int col_off,
    int N, int K, float* __restrict__ colsum)
{
  static_assert(MT == 64 || MT == 128, "MT");
  constexpr int MI = MT / 32;       // wave M-fragments (2 or 4)
  if (XTRA) {
    if (blockIdx.y == 4) {          // interp blocks: x in [0,128)
      const float* v256 = colsum;               // repurposed param
      f16* fb = (f16*)Cout;                     // fbuf16 base
      const int base = blockIdx.x * 16384 + (int)threadIdx.x;
#pragma unroll 4
      for (int i = 0; i < 64; i++) {
        const int idx = base + i * 256;
        const int c = idx & 255;
        const int t = (idx >> 8) & 1023;
        const int b = idx >> 18;
        float pos = ((float)t + 0.5f) * 0.03125f - 0.5f;
        pos = fminf(fmaxf(pos, 0.0f), 31.0f);
        const int lo = (int)floorf(pos);
        int hi = lo + 1; if (hi > 31) hi = 31;
        const float w = pos - (float)lo;
        const float vl = v256[(size_t)(b * 32 + lo) * 256 + c];
        const float vh = v256[(size_t)(b * 32 + hi) * 256 + c];
        fb[(size_t)(b * 1024 + t) * 512 + 256 + c] = (f16)(vl * (1.0f - w) + vh * w);
      }
      return;
    }
  }
  __shared__ __align__(16) f16 As[2][MT * 64];  // MT=128: 16 KB each
  __shared__ __align__(16) f16 Bs[2][64 * 64];  // 8 KB each
  const int tid = threadIdx.x;
  const int wave = tid >> 6, lane = tid & 63;
  const int wm = (wave >> 1) * (MT / 2);
  const int wn = (wave & 1) * 32;
  const int m0 = blockIdx.x * MT;     // transposed grid: x = M
  const int n0 = blockIdx.y * 64;     //                  y = N
  const int q = lane >> 4, r16 = lane & 15;

  // staging: granule c -> row c>>3, g = c&7. Thread handles c = tid + 256*j
  // -> rows rA0 + 32*j, same g (and same XOR term since (row&7) invariant).
  const int rA0 = tid >> 3, gA0 = tid & 7;
  const f16* pA = A + (size_t)(m0 + rA0) * K + gA0 * 8;
  const f16* pB = Wt + (size_t)(n0 + rA0) * K + gA0 * 8;
  const int sbase = rA0 * 128 + ((gA0 ^ (rA0 & 7)) * 16);

  f32x4 acc[MI][2];
#pragma unroll
  for (int mi = 0; mi < MI; mi++)
#pragma unroll
    for (int ni = 0; ni < 2; ni++) acc[mi][ni] = (f32x4)0.f;

  // prologue: load iter 0
  f16x8 ar[MI], br[2];
#pragma unroll
  for (int j = 0; j < MI; j++) ar[j] = *(const f16x8*)(pA + (size_t)j * 32 * K);
#pragma unroll
  for (int j = 0; j < 2; j++) br[j] = *(const f16x8*)(pB + (size_t)j * 32 * K);

  const int iters = K >> 6;
  int p = 0;
  for (int it = 0; it < iters; it++) {
#pragma unroll
    for (int j = 0; j < MI; j++)
      *(f16x8*)((char*)As[p] + sbase + j * 4096) = ar[j];
#pragma unroll
    for (int j = 0; j < 2; j++)
      *(f16x8*)((char*)Bs[p] + sbase + j * 4096) = br[j];
    if (it + 1 < iters) {
      const int ko = (it + 1) << 6;
#pragma unroll
      for (int j = 0; j < MI; j++) ar[j] = *(const f16x8*)(pA + (size_t)j * 32 * K + ko);
#pragma unroll
      for (int j = 0; j < 2; j++) br[j] = *(const f16x8*)(pB + (size_t)j * 32 * K + ko);
    }
    __syncthreads();
#pragma unroll
    for (int h = 0; h < 2; h++) {
      const int kg = h * 4 + q;
      f16x8 af[MI], bf[2];
#pragma unroll
      for (int mi = 0; mi < MI; mi++) {
        const int row = wm + mi * 16 + r16;
        af[mi] = *(const f16x8*)((char*)As[p] + row * 128 + ((kg ^ (row & 7)) * 16));
      }
#pragma unroll
      for (int ni = 0; ni < 2; ni++) {
        const int row = wn + ni * 16 + r16;
        bf[ni] = *(const f16x8*)((char*)Bs[p] + row * 128 + ((kg ^ (row & 7)) * 16));
      }
#pragma unroll
      for (int mi = 0; mi < MI; mi++)
#pragma unroll
        for (int ni = 0; ni < 2; ni++)
          acc[mi][ni] = __builtin_amdgcn_mfma_f32_16x16x32_f16(
              af[mi], bf[ni], acc[mi][ni], 0, 0, 0);
    }
    p ^= 1;
  }

#pragma unroll
  for (int ni = 0; ni < 2; ni++) {
    const int n = n0 + wn + ni * 16 + r16;
    const float bv = bias[n];
    float csum = 0.f;
#pragma unroll
    for (int mi = 0; mi < MI; mi++) {
#pragma unroll
      for (int rr = 0; rr < 4; rr++) {
        const int m = m0 + wm + mi * 16 + q * 4 + rr;
        float v = acc[mi][ni][rr] + bv;
        if (RELU) v = fmaxf(v, 0.f);
        if (OUT == 2) csum += v;
        ((f16*)Cout)[(size_t)m * ldc + col_off + n] = (f16)v;
      }
    }
    if (OUT == 2) {
      csum += __shfl_xor(csum, 16);
      csum += __shfl_xor(csum, 32);
      if (q == 0) atomicAdd(&colsum[(m0 >> 10) * 256 + n], csum);
    }
  }
}

// ============================================================================
// Merged: video conv7x7 tap-reduction (blocks [0,768)) + weight-transpose
// prep (blocks [768, 3786)). One dispatch, no inter-dependency.
// Video branch: image staged into LDS in 4 row-chunks with COALESCED float4
// loads (was: 56 scalar stride-2 global loads per thread, 64 lines per
// wave-instr). Row sums then read LDS. Chunk buffer 12.5 KB -> no occupancy
// impact on the transpose blocks sharing this kernel.
// ============================================================================
__global__ __launch_bounds__(256) void prep_video_kernel(
    const float* __restrict__ video, float* __restrict__ Sg,
    const float* __restrict__ w_ae, const float* __restrict__ w_a1,
    const float* __restrict__ w_a2, const float* __restrict__ w_f1,
    const float* __restrict__ w_f2, const float* __restrict__ heads_w,
    const float* __restrict__ heads_b,
    f16* __restrict__ wae_t, f16* __restrict__ wa1_t,
    f16* __restrict__ wa2_t, f16* __restrict__ wf1_t, f16* __restrict__ wf2_t,
    f16* __restrict__ wh_t, float* __restrict__ bp, float* __restrict__ colsum)
{
  if (blockIdx.x < 768) {
    const int img = blockIdx.x;
    const float* p = video + (size_t)img * 12544;
    __shared__ __align__(16) float imgc[28 * 112];   // 12.25 KB row-chunk
    __shared__ float rowS[2][112];
    __shared__ float c0s[112], c1s[112], c109s[112], c110s[112], c111s[112];
    __shared__ float base[14];
    __shared__ float sE[7], sO[7];
    const int t = threadIdx.x;
#pragma unroll 1
    for (int c = 0; c < 4; c++) {
      // coalesced load of rows [c*28, c*28+28): 784 float4
      for (int i = t; i < 784; i += 256)
        ((float4*)imgc)[i] = ((const float4*)(p + c * 3136))[i];
      __syncthreads();
      if (t < 56) {
        const int rl = t >> 1;
        const int r = c * 28 + rl;
        const int par = t & 1;
        const float* rp = imgc + rl * 112 + par;
        float s = 0.f;
#pragma unroll
        for (int i = 0; i < 56; i++) s += rp[2 * i];
        rowS[par][r] = s;
        if (par == 0) { c0s[r] = rp[0]; c110s[r] = rp[110]; }
        else { c1s[r] = rp[0]; c109s[r] = rp[108]; c111s[r] = rp[110]; }
      }
      __syncthreads();
    }
    if (t < 14) {
      const int arr = t >> 1;
      const int rp = t & 1;
      const float* src = (arr == 0) ? rowS[0] : (arr == 1) ? rowS[1] :
                         (arr == 2) ? c0s : (arr == 3) ? c1s :
                         (arr == 4) ? c109s : (arr == 5) ? c110s : c111s;
      float s = 0.f;
      for (int r = rp; r < 112; r += 2) s += src[r];
      base[t] = s;
    }
    __syncthreads();
    if (t < 7) {
      float se, so;
      switch (t) {
        case 0: se = base[2] - base[8] - base[12]; so = base[3] - base[9] - base[13]; break;
        case 1: se = base[0] - base[10];           so = base[1] - base[11];           break;
        case 2: se = base[2] - base[12];           so = base[3] - base[13];           break;
        case 3: se = base[0];                      so = base[1];                      break;
        case 4: se = base[2];                      so = base[3];                      break;
        case 5: se = base[0] - base[4];            so = base[1] - base[5];            break;
        default: se = base[2] - base[6];           so = base[3] - base[7];            break;
      }
      sE[t] = se; sO[t] = so;
    }
    __syncthreads();
    if (t < 49) {
      const int kh = t / 7, kw = t % 7;
      auto ccol = [&](int r) -> float {
        switch (kw) {
          case 0: return rowS[1][r] - c109s[r] - c111s[r];
          case 1: return rowS[0][r] - c110s[r];
          case 2: return rowS[1][r] - c111s[r];
          case 3: return rowS[0][r];
          case 4: return rowS[1][r];
          case 5: return rowS[0][r] - c0s[r];
          default: return rowS[1][r] - c1s[r];
        }
      };
      float v;
      switch (kh) {
        case 0: v = sO[kw] - ccol(109) - ccol(111); break;
        case 1: v = sE[kw] - ccol(110);             break;
        case 2: v = sO[kw] - ccol(111);             break;
        case 3: v = sE[kw];                         break;
        case 4: v = sO[kw];                         break;
        case 5: v = sE[kw] - ccol(0);               break;
        default: v = sO[kw] - ccol(1);              break;
      }
      Sg[(size_t)img * 49 + t] = v;
    }
    return;
  }
  // ---- weight transposes to [N][K] f16, bias copy, colsum zero ----
  int idx = (blockIdx.x - 768) * 256 + threadIdx.x;
  if (idx < 32768) {    // wae_t [256][128] (K padded 80->128)
    const int n = idx >> 7, k = idx & 127;
    wae_t[idx] = (f16)(k < 80 ? w_ae[k * 256 + n] : 0.f);
    return;
  }
  idx -= 32768;
  if (idx < 131072) { const int n = idx >> 8, k = idx & 255; wa1_t[idx] = (f16)w_a1[k * 512 + n]; return; }
  idx -= 131072;
  if (idx < 131072) { const int n = idx >> 9, k = idx & 511; wa2_t[idx] = (f16)w_a2[k * 256 + n]; return; }
  idx -= 131072;
  if (idx < 262144) { const int n = idx >> 9, k = idx & 511; wf1_t[idx] = (f16)w_f1[k * 512 + n]; return; }
  idx -= 262144;
  if (idx < 131072) { const int n = idx >> 9, k = idx & 511; wf2_t[idx] = (f16)w_f2[k * 256 + n]; return; }
  idx -= 131072;
  if (idx < 81920) {    // wh_t [320][256]
    const int n = idx >> 8, d = idx & 255;
    const int s = n / 80, o = n - s * 80;
    wh_t[idx] = (f16)heads_w[(size_t)(s * 256 + d) * 80 + o];
    return;
  }
  idx -= 81920;
  if (idx < 320) { bp[idx] = heads_b[idx]; return; }
  idx -= 320;
  if (idx < 2048) colsum[idx] = 0.f;
}

// ============================================================================
// Merged: vpool+FC (blocks [0,256)) and fused ae-GEMM + bias + LayerNorm
// (blocks [256,384), 64 rows each, full N=256 per block, K=128 single-shot).
// A staged straight from f32 audio (pad 80->128 on the fly). LDS 80 KB.
// Each wave owns 16 rows x 256 cols -> LN is a 16-lane shfl reduce.
// ============================================================================
__global__ __launch_bounds__(256) void vpool_aeln_kernel(
    const float* __restrict__ Sg, const float* __restrict__ conv_w,
    const float* __restrict__ conv_b, const float* __restrict__ w_vfc,
    const float* __restrict__ b_vfc, float* __restrict__ v256,
    const float* __restrict__ audio, const f16* __restrict__ wae_t,
    const float* __restrict__ b_ae, const float* __restrict__ ln_g,
    const float* __restrict__ ln_b, f16* __restrict__ a1)
{
  __shared__ __align__(16) f16 As[64 * 128];   // 16 KB (vpool reuses as vp)
  __shared__ __align__(16) f16 Bs[256 * 128];  // 64 KB
  const int tid = threadIdx.x;
  if (blockIdx.x < 256) {
    // ---- vpool: 49-tap conv + mean + FC 64->256 ----
    float* vp = (float*)As;
    const int n = blockIdx.x;
    if (tid < 64) {
      float acc = 0.f;
      const float* s = Sg + (size_t)n * 147;
#pragma unroll 7
      for (int k = 0; k < 147; k++) acc = fmaf(conv_w[tid * 147 + k], s[k], acc);
      vp[tid] = conv_b[tid] + acc * (1.0f / 3136.0f);
    }
    __syncthreads();
    float acc = 0.f;
#pragma unroll
    for (int k = 0; k < 64; k++) acc = fmaf(vp[k], w_vfc[k * 256 + tid], acc);
    v256[(size_t)n * 256 + tid] = acc + b_vfc[tid];
    return;
  }
  // ---- ae GEMM + LN ----
  const int m0 = (blockIdx.x - 256) * 64;
  const int wave = tid >> 6, lane = tid & 63;
  const int q = lane >> 4, r16 = lane & 15;
  // stage A [64][128] from audio f32 (10 real granules + 6 zero pad per row)
#pragma unroll
  for (int c = tid; c < 1024; c += 256) {
    const int row = c >> 4, g = c & 15;
    f16x8 val = (f16x8)(f16)0.f;
    if (g < 10) {
      const float* src = audio + (size_t)(m0 + row) * 80 + g * 8;
      const float4 u = *(const float4*)src;
      const float4 w = *(const float4*)(src + 4);
      val[0] = (f16)u.x; val[1] = (f16)u.y; val[2] = (f16)u.z; val[3] = (f16)u.w;
      val[4] = (f16)w.x; val[5] = (f16)w.y; val[6] = (f16)w.z; val[7] = (f16)w.w;
    }
    *(f16x8*)((char*)As + row * 256 + ((g ^ (row & 7)) * 16)) = val;
  }
  // stage B = wae_t [256][128]
#pragma unroll
  for (int c = tid; c < 4096; c += 256) {
    const int row = c >> 4, g = c & 15;
    *(f16x8*)((char*)Bs + row * 256 + ((g ^ (row & 7)) * 16)) =
        *(const f16x8*)(wae_t + (size_t)row * 128 + g * 8);
  }
  __syncthreads();
  const int wm = wave * 16;
  f32x4 acc[16];
#pragma unroll
  for (int nf = 0; nf < 16; nf++) acc[nf] = (f32x4)0.f;
#pragma unroll
  for (int kf = 0; kf < 4; kf++) {
    const int kg = kf * 4 + q;
    const int ar = wm + r16;
    const f16x8 af = *(const f16x8*)((char*)As + ar * 256 + ((kg ^ (ar & 7)) * 16));
#pragma unroll
    for (int nf = 0; nf < 16; nf++) {
      const int br = nf * 16 + r16;
      const f16x8 bf = *(const f16x8*)((char*)Bs + br * 256 + ((kg ^ (br & 7)) * 16));
      acc[nf] = __builtin_amdgcn_mfma_f32_16x16x32_f16(af, bf, acc[nf], 0, 0, 0);
    }
  }
  // bias add + per-row LN stats (rows q*4+rr, cols nf*16+r16)
  float rs[4] = {0.f, 0.f, 0.f, 0.f};
  float rq[4] = {0.f, 0.f, 0.f, 0.f};
#pragma unroll
  for (int nf = 0; nf < 16; nf++) {
    const float bv = b_ae[nf * 16 + r16];
#pragma unroll
    for (int rr = 0; rr < 4; rr++) {
      const float v = acc[nf][rr] + bv;
      acc[nf][rr] = v;
      rs[rr] += v; rq[rr] += v * v;
    }
  }
#pragma unroll
  for (int off = 1; off < 16; off <<= 1) {
#pragma unroll
    for (int rr = 0; rr < 4; rr++) {
      rs[rr] += __shfl_xor(rs[rr], off);
      rq[rr] += __shfl_xor(rq[rr], off);
    }
  }
  float mu[4], ri[4];
#pragma unroll
  for (int rr = 0; rr < 4; rr++) {
    mu[rr] = rs[rr] * (1.0f / 256.0f);
    const float var = rq[rr] * (1.0f / 256.0f) - mu[rr] * mu[rr];
    ri[rr] = rsqrtf(var + 1e-5f);
  }
#pragma unroll
  for (int nf = 0; nf < 16; nf++) {
    const int col = nf * 16 + r16;
    const float g = ln_g[col], b = ln_b[col];
#pragma unroll
    for (int rr = 0; rr < 4; rr++) {
      const int row = m0 + wm + q * 4 + rr;
      a1[(size_t)row * 256 + col] = (f16)((acc[nf][rr] - mu[rr]) * ri[rr] * g + b);
    }
  }
}

// ============================================================================
// Heads GEMM + energy. Grid TRANSPOSED: (128 m-blocks, 4 speakers) so XCD =
// m-strip (A shared within XCD). N-tile = 80 (one speaker), K=256
// single-shot, LDS 72 KB. Epilogue: specs store in [B,S,T,80] layout +
// per-row 80-col sum -> energy (no atomics, no re-read).
// ============================================================================
__global__ __launch_bounds__(256) void heads_energy_kernel(
    const f16* __restrict__ A, const f16* __restrict__ Wt,
    const float* __restrict__ bias, float* __restrict__ specs,
    float* __restrict__ energy)
{
  __shared__ __align__(16) f16 As[64 * 256];   // 32 KB
  __shared__ __align__(16) f16 Bs[80 * 256];   // 40 KB
  const int tid = threadIdx.x;
  const int s = blockIdx.y;
  const int m0 = blockIdx.x * 64;
  const int wave = tid >> 6, lane = tid & 63;
  const int q = lane >> 4, r16 = lane & 15;
  // stage A [64][256]
#pragma unroll
  for (int c = tid; c < 2048; c += 256) {
    const int row = c >> 5, g = c & 31;
    *(f16x8*)((char*)As + row * 512 + ((g ^ (row & 7)) * 16)) =
        *(const f16x8*)(A + (size_t)(m0 + row) * 256 + g * 8);
  }
  // stage B [80][256] = wh_t rows s*80 .. s*80+79
#pragma unroll
  for (int c = tid; c < 2560; c += 256) {
    const int row = c >> 5, g = c & 31;
    *(f16x8*)((char*)Bs + row * 512 + ((g ^ (row & 7)) * 16)) =
        *(const f16x8*)(Wt + (size_t)(s * 80 + row) * 256 + g * 8);
  }
  __syncthreads();
  const int wm = wave * 16;
  f32x4 acc[5];
#pragma unroll
  for (int nf = 0; nf < 5; nf++) acc[nf] = (f32x4)0.f;
#pragma unroll
  for (int kf = 0; kf < 8; kf++) {
    const int kg = kf * 4 + q;
    const int ar = wm + r16;
    const f16x8 af = *(const f16x8*)((char*)As + ar * 512 + ((kg ^ (ar & 7)) * 16));
#pragma unroll
    for (int nf = 0; nf < 5; nf++) {
      const int br = nf * 16 + r16;
      const f16x8 bf = *(const f16x8*)((char*)Bs + br * 512 + ((kg ^ (br & 7)) * 16));
      acc[nf] = __builtin_amdgcn_mfma_f32_16x16x32_f16(af, bf, acc[nf], 0, 0, 0);
    }
  }
  // epilogue: store specs + row-sum -> energy
  float bv[5];
#pragma unroll
  for (int nf = 0; nf < 5; nf++) bv[nf] = bias[s * 80 + nf * 16 + r16];
  float rs[4] = {0.f, 0.f, 0.f, 0.f};
#pragma unroll
  for (int rr = 0; rr < 4; rr++) {
    const int row = m0 + wm + q * 4 + rr;
    const int b_ = row >> 10, t_ = row & 1023;
    float* dst = specs + ((size_t)((b_ * 4 + s) * 1024 + t_)) * 80;
#pragma unroll
    for (int nf = 0; nf < 5; nf++) {
      const float v = acc[nf][rr] + bv[nf];
      rs[rr] += v;
      dst[nf * 16 + r16] = v;
    }
  }
#pragma unroll
  for (int off = 1; off < 16; off <<= 1) {
#pragma unroll
    for (int rr = 0; rr < 4; rr++) rs[rr] += __shfl_xor(rs[rr], off);
  }
  if (r16 == 0) {
#pragma unroll
    for (int rr = 0; rr < 4; rr++) {
      const int row = m0 + wm + q * 4 + rr;
      const int b_ = row >> 10, t_ = row & 1023;
      energy[((b_ * 4 + s) << 10) + t_] = rs[rr];
    }
  }
}

// ============================================================================
// Waveforms (threefry2x32 + fast erfinv) + speaker-logits tail block.
// 4 elements per thread: 4 independent threefry chains (ILP), one int-div,
// float4 store. log1pf replaced by factored fast log:
//   w = -log1p(-u^2)  ==  -__logf((1-u)*(1+u))   (Sterbenz: no cancellation)
// ============================================================================
__device__ __forceinline__ unsigned rotl32(unsigned x, int d) {
  return (x << d) | (x >> (32 - d));
}

__device__ __forceinline__ float erfinv_fast(float x) {
  const float t = (1.0f - x) * (1.0f + x);   // = 1 - x^2, exact-ish
  float w = -__logf(t);
  float p;
  if (w < 5.0f) {
    w = w - 2.5f;
    p = 2.81022636e-08f;
    p = fmaf(p, w, 3.43273939e-07f);
    p = fmaf(p, w, -3.5233877e-06f);
    p = fmaf(p, w, -4.39150654e-06f);
    p = fmaf(p, w, 0.00021858087f);
    p = fmaf(p, w, -0.00125372503f);
    p = fmaf(p, w, -0.00417768164f);
    p = fmaf(p, w, 0.246640727f);
    p = fmaf(p, w, 1.50140941f);
  } else {
    w = sqrtf(w) - 3.0f;
    p = -0.000200214257f;
    p = fmaf(p, w, 0.000100950558f);
    p = fmaf(p, w, 0.00134934322f);
    p = fmaf(p, w, -0.00367342844f);
    p = fmaf(p, w, 0.00573950773f);
    p = fmaf(p, w, -0.0076224613f);
    p = fmaf(p, w, 0.00943887047f);
    p = fmaf(p, w, 1.00167406f);
    p = fmaf(p, w, 2.83297682f);
  }
  return p * x;
}

__global__ __launch_bounds__(256) void waveform_kernel(
    const float* __restrict__ energy, float* __restrict__ out,
    const float* __restrict__ colsum, const float* __restrict__ w_spk,
    const float* __restrict__ b_spk, float* __restrict__ logits)
{
  if (blockIdx.x == 5120) {
    // speaker logits tail
    const int idx = threadIdx.x;
    if (idx < 32) {
      const int b = idx >> 2, s = idx & 3;
      const float* cs = colsum + b * 256;
      float acc = 0.f;
#pragma unroll 8
      for (int d = 0; d < 256; d++)
        acc = fmaf(cs[d] * (1.0f / 1024.0f), w_spk[d * 4 + s], acc);
      logits[b * 4 + s] = acc + b_spk[s];
    }
    return;
  }
  const unsigned base = (blockIdx.x * 256 + threadIdx.x) * 4;  // [0, 5242880)
  const unsigned ks0 = 0u, ks1 = 1234u;
  const unsigned ks2 = 0x1BD11BDAu ^ ks0 ^ ks1;
  unsigned x0[4], x1[4];
#pragma unroll
  for (int j = 0; j < 4; j++) { x0[j] = ks0; x1[j] = base + (unsigned)j + ks1; }
#define TFR(r)                                                     \
  _Pragma("unroll") for (int j = 0; j < 4; j++) {                  \
    x0[j] += x1[j]; x1[j] = rotl32(x1[j], r); x1[j] ^= x0[j];      \
  }
#define TFK(ka, kb)                                                \
  _Pragma("unroll") for (int j = 0; j < 4; j++) {                  \
    x0[j] += (ka); x1[j] += (kb);                                  \
  }
  TFR(13) TFR(15) TFR(26) TFR(6)  TFK(ks1, ks2 + 1u)
  TFR(17) TFR(29) TFR(16) TFR(24) TFK(ks2, ks0 + 2u)
  TFR(13) TFR(15) TFR(26) TFR(6)  TFK(ks0, ks1 + 3u)
  TFR(17) TFR(29) TFR(16) TFR(24) TFK(ks1, ks2 + 4u)
  TFR(13) TFR(15) TFR(26) TFR(6)  TFK(ks2, ks0 + 5u)
#undef TFR
#undef TFK
  // all 4 elements share one waveform row (163840 % 4 == 0)
  const unsigned i0 = base % 163840u;
  const unsigned bs = base / 163840u;
  const float* e = energy + (size_t)bs * 1024;
  float4 o;
#pragma unroll
  for (int j = 0; j < 4; j++) {
    const unsigned bits = x0[j] ^ x1[j];
    const float f = __uint_as_float((bits >> 9) | 0x3f800000u) - 1.0f;
    const float minv = -0.99999994f;
    const float u = fmaxf(minv, fmaf(f, 2.0f, minv));
    const float noise = 1.41421354f * erfinv_fast(u) * 0.1f;
    float pos = ((float)(i0 + j) + 0.5f) * 0.00625f - 0.5f;
    pos = fminf(fmaxf(pos, 0.0f), 1023.0f);
    const int lo = (int)floorf(pos);
    int hi = lo + 1; if (hi > 1023) hi = 1023;
    const float w = pos - (float)lo;
    const float ev = e[lo] * (1.0f - w) + e[hi] * w;
    ((float*)&o)[j] = noise * fmaf(ev, 0.5f, 0.5f);
  }
  *(float4*)(out + base) = o;
}

// ============================================================================
extern "C" void kernel_launch(void* const* d_in, const int* in_sizes, int n_in,
                              void* d_out, int out_size, void* d_ws, size_t ws_size,
                              hipStream_t stream)
{
  (void)in_sizes; (void)n_in; (void)out_size; (void)ws_size;
  const float* audio   = (const float*)d_in[0];
  const float* video   = (const float*)d_in[1];
  const float* w_ae    = (const float*)d_in[2];
  const float* b_ae    = (const float*)d_in[3];
  const float* ln_g    = (const float*)d_in[4];
  const float* ln_b    = (const float*)d_in[5];
  const float* w_a1    = (const float*)d_in[6];
  const float* b_a1    = (const float*)d_in[7];
  const float* w_a2    = (const float*)d_in[8];
  const float* b_a2    = (const float*)d_in[9];
  const float* conv_w  = (const float*)d_in[10];
  const float* conv_b  = (const float*)d_in[11];
  const float* w_vfc   = (const float*)d_in[12];
  const float* b_vfc   = (const float*)d_in[13];
  const float* w_f1    = (const float*)d_in[14];
  const float* b_f1    = (const float*)d_in[15];
  const float* w_f2    = (const float*)d_in[16];
  const float* b_f2    = (const float*)d_in[17];
  const float* heads_w = (const float*)d_in[18];
  const float* heads_b = (const float*)d_in[19];
  const float* w_spk   = (const float*)d_in[20];
  const float* b_spk   = (const float*)d_in[21];

  float* ws = (float*)d_ws;
  float* colsum = ws + 2097152;       // 2,048
  float* Sg     = ws + 2099200;       // 37,632
  float* v256   = ws + 2136832;       // 65,536
  float* energy = ws + 2202368;       // 32,768
  float* bp     = ws + 2235136;       // 320  (+pad to 2235456)
  f16* fh = (f16*)(ws + 2235456);
  f16* a1     = fh;                   // 2,097,152 f16
  f16* h16    = a1 + 2097152;         // 4,194,304
  f16* fbuf16 = h16 + 4194304;        // 4,194,304
  f16* a_h    = fbuf16 + 4194304;     // (retired)
  f16* wae_t  = a_h + 1048576;        //    32,768
  f16* wa1_t  = wae_t + 32768;        //   131,072
  f16* wa2_t  = wa1_t + 131072;       //   131,072
  f16* wf1_t  = wa2_t + 131072;       //   262,144
  f16* wf2_t  = wf1_t + 262144;       //   131,072
  f16* wh_t   = wf2_t + 131072;       //    81,920

  float* out_wave   = (float*)d_out;           // 5,242,880
  float* out_specs  = out_wave + 5242880;      // 2,621,440
  float* out_logits = out_specs + 2621440;     // 32

  // 1. video tap-reduce + weight transposes + colsum zero
  prep_video_kernel<<<3786, 256, 0, stream>>>(video, Sg, w_ae, w_a1, w_a2,
                                              w_f1, w_f2, heads_w, heads_b,
                                              wae_t, wa1_t, wa2_t, wf1_t,
                                              wf2_t, wh_t, bp, colsum);
  // 2. vpool+FC  ||  ae GEMM + bias + LayerNorm -> a1 (f16)
  vpool_aeln_kernel<<<384, 256, 0, stream>>>(Sg, conv_w, conv_b, w_vfc, b_vfc,
                                             v256, audio, wae_t, b_ae,
                                             ln_g, ln_b, a1);
  // 3. a1 MLP up: relu(a1 @ w_a1)   [grid: x=M/128, y=N/64]
  hgemm<128, 1, 1><<<dim3(64, 8), 256, 0, stream>>>(a1, wa1_t, b_a1, h16, 512, 0, 512, 256, nullptr);
  // 4. a2 MLP down -> fbuf cols [0,256)  +  video interp (y==4) -> cols [256,512)
  hgemm<64, 0, 1, 1><<<dim3(128, 5), 256, 0, stream>>>(h16, wa2_t, b_a2, fbuf16, 512, 0, 256, 512, v256);
  // 5. fusion up: relu(fbuf @ w_f1)
  hgemm<128, 1, 1><<<dim3(64, 8), 256, 0, stream>>>(fbuf16, wf1_t, b_f1, h16, 512, 0, 512, 512, nullptr);
  // 6. fusion down -> a1 (f16) + colsum atomics
  hgemm<64, 0, 2><<<dim3(128, 4), 256, 0, stream>>>(h16, wf2_t, b_f2, a1, 256, 0, 256, 512, colsum);
  // 7. heads -> specs [B,S,T,80] + energy row-sums  [grid: x=M/64, y=speaker]
  heads_energy_kernel<<<dim3(128, 4), 256, 0, stream>>>(a1, wh_t, bp, out_specs, energy);
  // 8. waveforms + speaker logits (tail block)
  waveform_kernel<<<5121, 256, 0, stream>>>(energy, out_wave, colsum, w_spk,
                                            b_spk, out_logits);
}

// Round 6
// 214.804 us; speedup vs baseline: 2.4702x; 1.0078x over previous
//
#include <hip/hip_runtime.h>
#include <hip/hip_bf16.h>
#include <math.h>

typedef _Float16 f16;
typedef f16 f16x8 __attribute__((ext_vector_type(8)));
typedef f16 f16x4 __attribute__((ext_vector_type(4)));
typedef float f32x4 __attribute__((ext_vector_type(4)));

// ============================================================================
// Noise generation (threefry2x32, key=[0,1234], + fast erfinv).
// Pure function of element index -> relocatable to any dispatch.
// ============================================================================
__device__ __forceinline__ unsigned rotl32(unsigned x, int d) {
  return (x << d) | (x >> (32 - d));
}

__device__ __forceinline__ float erfinv_fast(float x) {
  const float t = (1.0f - x) * (1.0f + x);   // = 1 - x^2, no cancellation
  float w = -__logf(t);
  float p;
  if (w < 5.0f) {
    w = w - 2.5f;
    p = 2.81022636e-08f;
    p = fmaf(p, w, 3.43273939e-07f);
    p = fmaf(p, w, -3.5233877e-06f);
    p = fmaf(p, w, -4.39150654e-06f);
    p = fmaf(p, w, 0.00021858087f);
    p = fmaf(p, w, -0.00125372503f);
    p = fmaf(p, w, -0.00417768164f);
    p = fmaf(p, w, 0.246640727f);
    p = fmaf(p, w, 1.50140941f);
  } else {
    w = sqrtf(w) - 3.0f;
    p = -0.000200214257f;
    p = fmaf(p, w, 0.000100950558f);
    p = fmaf(p, w, 0.00134934322f);
    p = fmaf(p, w, -0.00367342844f);
    p = fmaf(p, w, 0.00573950773f);
    p = fmaf(p, w, -0.0076224613f);
    p = fmaf(p, w, 0.00943887047f);
    p = fmaf(p, w, 1.00167406f);
    p = fmaf(p, w, 2.83297682f);
  }
  return p * x;
}

// One noise unit = 256 threads x 4 elements (float4 store), unit index u.
__device__ __forceinline__ void noise_unit(float* __restrict__ noise, unsigned u) {
  const unsigned base = (u * 256u + threadIdx.x) * 4u;
  const unsigned ks0 = 0u, ks1 = 1234u;
  const unsigned ks2 = 0x1BD11BDAu ^ ks0 ^ ks1;
  unsigned x0[4], x1[4];
#pragma unroll
  for (int j = 0; j < 4; j++) { x0[j] = ks0; x1[j] = base + (unsigned)j + ks1; }
#define TFR(r)                                                     \
  _Pragma("unroll") for (int j = 0; j < 4; j++) {                  \
    x0[j] += x1[j]; x1[j] = rotl32(x1[j], r); x1[j] ^= x0[j];      \
  }
#define TFK(ka, kb)                                                \
  _Pragma("unroll") for (int j = 0; j < 4; j++) {                  \
    x0[j] += (ka); x1[j] += (kb);                                  \
  }
  TFR(13) TFR(15) TFR(26) TFR(6)  TFK(ks1, ks2 + 1u)
  TFR(17) TFR(29) TFR(16) TFR(24) TFK(ks2, ks0 + 2u)
  TFR(13) TFR(15) TFR(26) TFR(6)  TFK(ks0, ks1 + 3u)
  TFR(17) TFR(29) TFR(16) TFR(24) TFK(ks1, ks2 + 4u)
  TFR(13) TFR(15) TFR(26) TFR(6)  TFK(ks2, ks0 + 5u)
#undef TFR
#undef TFK
  float4 o;
#pragma unroll
  for (int j = 0; j < 4; j++) {
    const unsigned bits = x0[j] ^ x1[j];
    const float f = __uint_as_float((bits >> 9) | 0x3f800000u) - 1.0f;
    const float minv = -0.99999994f;
    const float uu = fmaxf(minv, fmaf(f, 2.0f, minv));
    ((float*)&o)[j] = 1.41421354f * erfinv_fast(uu) * 0.1f;
  }
  *(float4*)(noise + base) = o;
}

// ============================================================================
// fp16 MFMA GEMM: C[M,N] = A[M,K](f16) @ Wt[N,K]^T(f16) + bias(f32)
// Tile MT(M) x 64(N), MT in {64,128}. BK=64, 256 threads = 4 waves,
// wave tile (MT/2) x 32. Double-buffered LDS ping-pong, ONE barrier per
// K-iter, register prefetch.
// GRID IS TRANSPOSED: blockIdx.x = M-block, blockIdx.y = N-block.
// gridDim.x is a multiple of 8 -> all N-blocks sharing an A-tile land on
// the SAME XCD (bid = x + gridDim.x*y, gridDim.x % 8 == 0) -> A is fetched
// once per XCD instead of 8x.
// OUT: 1 = f16 store; 2 = f16 store + colsum atomics (speaker).
// XTRA: blockIdx.y == 4 runs the video temporal-interp (v256 -> fbuf cols
//       256..511) instead of GEMM work; colsum param carries v256.
// ============================================================================
template<int MT, int RELU, int OUT, int XTRA = 0>
__global__ __launch_bounds__(256) void hgemm(
    const f16* __restrict__ A, const f16* __restrict__ Wt,
    const float* __restrict__ bias,
    void* __restrict__ Cout, int ldc, int col_off,
    int N, int K, float* __restrict__ colsum)
{
  static_assert(MT == 64 || MT == 128, "MT");
  constexpr int MI = MT / 32;       // wave M-fragments (2 or 4)
  if (XTRA) {
    if (blockIdx.y == 4) {          // interp blocks: x in [0,128)
      const float* v256 = colsum;               // repurposed param
      f16* fb = (f16*)Cout;                     // fbuf16 base
      const int base = blockIdx.x * 16384 + (int)threadIdx.x;
#pragma unroll 4
      for (int i = 0; i < 64; i++) {
        const int idx = base + i * 256;
        const int c = idx & 255;
        const int t = (idx >> 8) & 1023;
        const int b = idx >> 18;
        float pos = ((float)t + 0.5f) * 0.03125f - 0.5f;
        pos = fminf(fmaxf(pos, 0.0f), 31.0f);
        const int lo = (int)floorf(pos);
        int hi = lo + 1; if (hi > 31) hi = 31;
        const float w = pos - (float)lo;
        const float vl = v256[(size_t)(b * 32 + lo) * 256 + c];
        const float vh = v256[(size_t)(b * 32 + hi) * 256 + c];
        fb[(size_t)(b * 1024 + t) * 512 + 256 + c] = (f16)(vl * (1.0f - w) + vh * w);
      }
      return;
    }
  }
  __shared__ __align__(16) f16 As[2][MT * 64];  // MT=128: 16 KB each
  __shared__ __align__(16) f16 Bs[2][64 * 64];  // 8 KB each
  const int tid = threadIdx.x;
  const int wave = tid >> 6, lane = tid & 63;
  const int wm = (wave >> 1) * (MT / 2);
  const int wn = (wave & 1) * 32;
  const int m0 = blockIdx.x * MT;     // transposed grid: x = M
  const int n0 = blockIdx.y * 64;     //                  y = N
  const int q = lane >> 4, r16 = lane & 15;

  const int rA0 = tid >> 3, gA0 = tid & 7;
  const f16* pA = A + (size_t)(m0 + rA0) * K + gA0 * 8;
  const f16* pB = Wt + (size_t)(n0 + rA0) * K + gA0 * 8;
  const int sbase = rA0 * 128 + ((gA0 ^ (rA0 & 7)) * 16);

  f32x4 acc[MI][2];
#pragma unroll
  for (int mi = 0; mi < MI; mi++)
#pragma unroll
    for (int ni = 0; ni < 2; ni++) acc[mi][ni] = (f32x4)0.f;

  // prologue: load iter 0
  f16x8 ar[MI], br[2];
#pragma unroll
  for (int j = 0; j < MI; j++) ar[j] = *(const f16x8*)(pA + (size_t)j * 32 * K);
#pragma unroll
  for (int j = 0; j < 2; j++) br[j] = *(const f16x8*)(pB + (size_t)j * 32 * K);

  const int iters = K >> 6;
  int p = 0;
  for (int it = 0; it < iters; it++) {
#pragma unroll
    for (int j = 0; j < MI; j++)
      *(f16x8*)((char*)As[p] + sbase + j * 4096) = ar[j];
#pragma unroll
    for (int j = 0; j < 2; j++)
      *(f16x8*)((char*)Bs[p] + sbase + j * 4096) = br[j];
    if (it + 1 < iters) {
      const int ko = (it + 1) << 6;
#pragma unroll
      for (int j = 0; j < MI; j++) ar[j] = *(const f16x8*)(pA + (size_t)j * 32 * K + ko);
#pragma unroll
      for (int j = 0; j < 2; j++) br[j] = *(const f16x8*)(pB + (size_t)j * 32 * K + ko);
    }
    __syncthreads();
#pragma unroll
    for (int h = 0; h < 2; h++) {
      const int kg = h * 4 + q;
      f16x8 af[MI], bf[2];
#pragma unroll
      for (int mi = 0; mi < MI; mi++) {
        const int row = wm + mi * 16 + r16;
        af[mi] = *(const f16x8*)((char*)As[p] + row * 128 + ((kg ^ (row & 7)) * 16));
      }
#pragma unroll
      for (int ni = 0; ni < 2; ni++) {
        const int row = wn + ni * 16 + r16;
        bf[ni] = *(const f16x8*)((char*)Bs[p] + row * 128 + ((kg ^ (row & 7)) * 16));
      }
#pragma unroll
      for (int mi = 0; mi < MI; mi++)
#pragma unroll
        for (int ni = 0; ni < 2; ni++)
          acc[mi][ni] = __builtin_amdgcn_mfma_f32_16x16x32_f16(
              af[mi], bf[ni], acc[mi][ni], 0, 0, 0);
    }
    p ^= 1;
  }

#pragma unroll
  for (int ni = 0; ni < 2; ni++) {
    const int n = n0 + wn + ni * 16 + r16;
    const float bv = bias[n];
    float csum = 0.f;
#pragma unroll
    for (int mi = 0; mi < MI; mi++) {
#pragma unroll
      for (int rr = 0; rr < 4; rr++) {
        const int m = m0 + wm + mi * 16 + q * 4 + rr;
        float v = acc[mi][ni][rr] + bv;
        if (RELU) v = fmaxf(v, 0.f);
        if (OUT == 2) csum += v;
        ((f16*)Cout)[(size_t)m * ldc + col_off + n] = (f16)v;
      }
    }
    if (OUT == 2) {
      csum += __shfl_xor(csum, 16);
      csum += __shfl_xor(csum, 32);
      if (q == 0) atomicAdd(&colsum[(m0 >> 10) * 256 + n], csum);
    }
  }
}

// ============================================================================
// Merged: video conv7x7 tap-reduction (blocks [0,768)) + weight-transpose
// prep (blocks [768, 3786)) + NOISE GENERATION (blocks [3786, 8906)).
// Noise is pure-VALU and overlaps the memory-bound video/transpose blocks.
// ============================================================================
__global__ __launch_bounds__(256) void prep_video_kernel(
    const float* __restrict__ video, float* __restrict__ Sg,
    const float* __restrict__ w_ae, const float* __restrict__ w_a1,
    const float* __restrict__ w_a2, const float* __restrict__ w_f1,
    const float* __restrict__ w_f2, const float* __restrict__ heads_w,
    const float* __restrict__ heads_b,
    f16* __restrict__ wae_t, f16* __restrict__ wa1_t,
    f16* __restrict__ wa2_t, f16* __restrict__ wf1_t, f16* __restrict__ wf2_t,
    f16* __restrict__ wh_t, float* __restrict__ bp, float* __restrict__ colsum,
    float* __restrict__ noise)
{
  if (blockIdx.x >= 3786) {
    noise_unit(noise, blockIdx.x - 3786);
    return;
  }
  if (blockIdx.x < 768) {
    const int img = blockIdx.x;
    const float* p = video + (size_t)img * 12544;
    __shared__ __align__(16) float imgc[28 * 112];   // 12.25 KB row-chunk
    __shared__ float rowS[2][112];
    __shared__ float c0s[112], c1s[112], c109s[112], c110s[112], c111s[112];
    __shared__ float base[14];
    __shared__ float sE[7], sO[7];
    const int t = threadIdx.x;
#pragma unroll 1
    for (int c = 0; c < 4; c++) {
      for (int i = t; i < 784; i += 256)
        ((float4*)imgc)[i] = ((const float4*)(p + c * 3136))[i];
      __syncthreads();
      if (t < 56) {
        const int rl = t >> 1;
        const int r = c * 28 + rl;
        const int par = t & 1;
        const float* rp = imgc + rl * 112 + par;
        float s = 0.f;
#pragma unroll
        for (int i = 0; i < 56; i++) s += rp[2 * i];
        rowS[par][r] = s;
        if (par == 0) { c0s[r] = rp[0]; c110s[r] = rp[110]; }
        else { c1s[r] = rp[0]; c109s[r] = rp[108]; c111s[r] = rp[110]; }
      }
      __syncthreads();
    }
    if (t < 14) {
      const int arr = t >> 1;
      const int rp = t & 1;
      const float* src = (arr == 0) ? rowS[0] : (arr == 1) ? rowS[1] :
                         (arr == 2) ? c0s : (arr == 3) ? c1s :
                         (arr == 4) ? c109s : (arr == 5) ? c110s : c111s;
      float s = 0.f;
      for (int r = rp; r < 112; r += 2) s += src[r];
      base[t] = s;
    }
    __syncthreads();
    if (t < 7) {
      float se, so;
      switch (t) {
        case 0: se = base[2] - base[8] - base[12]; so = base[3] - base[9] - base[13]; break;
        case 1: se = base[0] - base[10];           so = base[1] - base[11];           break;
        case 2: se = base[2] - base[12];           so = base[3] - base[13];           break;
        case 3: se = base[0];                      so = base[1];                      break;
        case 4: se = base[2];                      so = base[3];                      break;
        case 5: se = base[0] - base[4];            so = base[1] - base[5];            break;
        default: se = base[2] - base[6];           so = base[3] - base[7];            break;
      }
      sE[t] = se; sO[t] = so;
    }
    __syncthreads();
    if (t < 49) {
      const int kh = t / 7, kw = t % 7;
      auto ccol = [&](int r) -> float {
        switch (kw) {
          case 0: return rowS[1][r] - c109s[r] - c111s[r];
          case 1: return rowS[0][r] - c110s[r];
          case 2: return rowS[1][r] - c111s[r];
          case 3: return rowS[0][r];
          case 4: return rowS[1][r];
          case 5: return rowS[0][r] - c0s[r];
          default: return rowS[1][r] - c1s[r];
        }
      };
      float v;
      switch (kh) {
        case 0: v = sO[kw] - ccol(109) - ccol(111); break;
        case 1: v = sE[kw] - ccol(110);             break;
        case 2: v = sO[kw] - ccol(111);             break;
        case 3: v = sE[kw];                         break;
        case 4: v = sO[kw];                         break;
        case 5: v = sE[kw] - ccol(0);               break;
        default: v = sO[kw] - ccol(1);              break;
      }
      Sg[(size_t)img * 49 + t] = v;
    }
    return;
  }
  // ---- weight transposes to [N][K] f16, bias copy, colsum zero ----
  int idx = (blockIdx.x - 768) * 256 + threadIdx.x;
  if (idx < 32768) {    // wae_t [256][128] (K padded 80->128)
    const int n = idx >> 7, k = idx & 127;
    wae_t[idx] = (f16)(k < 80 ? w_ae[k * 256 + n] : 0.f);
    return;
  }
  idx -= 32768;
  if (idx < 131072) { const int n = idx >> 8, k = idx & 255; wa1_t[idx] = (f16)w_a1[k * 512 + n]; return; }
  idx -= 131072;
  if (idx < 131072) { const int n = idx >> 9, k = idx & 511; wa2_t[idx] = (f16)w_a2[k * 256 + n]; return; }
  idx -= 131072;
  if (idx < 262144) { const int n = idx >> 9, k = idx & 511; wf1_t[idx] = (f16)w_f1[k * 512 + n]; return; }
  idx -= 262144;
  if (idx < 131072) { const int n = idx >> 9, k = idx & 511; wf2_t[idx] = (f16)w_f2[k * 256 + n]; return; }
  idx -= 131072;
  if (idx < 81920) {    // wh_t [320][256]
    const int n = idx >> 8, d = idx & 255;
    const int s = n / 80, o = n - s * 80;
    wh_t[idx] = (f16)heads_w[(size_t)(s * 256 + d) * 80 + o];
    return;
  }
  idx -= 81920;
  if (idx < 320) { bp[idx] = heads_b[idx]; return; }
  idx -= 320;
  if (idx < 2048) colsum[idx] = 0.f;
}

// ============================================================================
// Merged: vpool+FC (blocks [0,256)) and fused ae-GEMM + bias + LayerNorm
// (blocks [256,384), 64 rows each, full N=256 per block, K=128 single-shot).
// ============================================================================
__global__ __launch_bounds__(256) void vpool_aeln_kernel(
    const float* __restrict__ Sg, const float* __restrict__ conv_w,
    const float* __restrict__ conv_b, const float* __restrict__ w_vfc,
    const float* __restrict__ b_vfc, float* __restrict__ v256,
    const float* __restrict__ audio, const f16* __restrict__ wae_t,
    const float* __restrict__ b_ae, const float* __restrict__ ln_g,
    const float* __restrict__ ln_b, f16* __restrict__ a1)
{
  __shared__ __align__(16) f16 As[64 * 128];   // 16 KB (vpool reuses as vp)
  __shared__ __align__(16) f16 Bs[256 * 128];  // 64 KB
  const int tid = threadIdx.x;
  if (blockIdx.x < 256) {
    float* vp = (float*)As;
    const int n = blockIdx.x;
    if (tid < 64) {
      float acc = 0.f;
      const float* s = Sg + (size_t)n * 147;
#pragma unroll 7
      for (int k = 0; k < 147; k++) acc = fmaf(conv_w[tid * 147 + k], s[k], acc);
      vp[tid] = conv_b[tid] + acc * (1.0f / 3136.0f);
    }
    __syncthreads();
    float acc = 0.f;
#pragma unroll
    for (int k = 0; k < 64; k++) acc = fmaf(vp[k], w_vfc[k * 256 + tid], acc);
    v256[(size_t)n * 256 + tid] = acc + b_vfc[tid];
    return;
  }
  // ---- ae GEMM + LN ----
  const int m0 = (blockIdx.x - 256) * 64;
  const int wave = tid >> 6, lane = tid & 63;
  const int q = lane >> 4, r16 = lane & 15;
#pragma unroll
  for (int c = tid; c < 1024; c += 256) {
    const int row = c >> 4, g = c & 15;
    f16x8 val = (f16x8)(f16)0.f;
    if (g < 10) {
      const float* src = audio + (size_t)(m0 + row) * 80 + g * 8;
      const float4 u = *(const float4*)src;
      const float4 w = *(const float4*)(src + 4);
      val[0] = (f16)u.x; val[1] = (f16)u.y; val[2] = (f16)u.z; val[3] = (f16)u.w;
      val[4] = (f16)w.x; val[5] = (f16)w.y; val[6] = (f16)w.z; val[7] = (f16)w.w;
    }
    *(f16x8*)((char*)As + row * 256 + ((g ^ (row & 7)) * 16)) = val;
  }
#pragma unroll
  for (int c = tid; c < 4096; c += 256) {
    const int row = c >> 4, g = c & 15;
    *(f16x8*)((char*)Bs + row * 256 + ((g ^ (row & 7)) * 16)) =
        *(const f16x8*)(wae_t + (size_t)row * 128 + g * 8);
  }
  __syncthreads();
  const int wm = wave * 16;
  f32x4 acc[16];
#pragma unroll
  for (int nf = 0; nf < 16; nf++) acc[nf] = (f32x4)0.f;
#pragma unroll
  for (int kf = 0; kf < 4; kf++) {
    const int kg = kf * 4 + q;
    const int ar = wm + r16;
    const f16x8 af = *(const f16x8*)((char*)As + ar * 256 + ((kg ^ (ar & 7)) * 16));
#pragma unroll
    for (int nf = 0; nf < 16; nf++) {
      const int br = nf * 16 + r16;
      const f16x8 bf = *(const f16x8*)((char*)Bs + br * 256 + ((kg ^ (br & 7)) * 16));
      acc[nf] = __builtin_amdgcn_mfma_f32_16x16x32_f16(af, bf, acc[nf], 0, 0, 0);
    }
  }
  float rs[4] = {0.f, 0.f, 0.f, 0.f};
  float rq[4] = {0.f, 0.f, 0.f, 0.f};
#pragma unroll
  for (int nf = 0; nf < 16; nf++) {
    const float bv = b_ae[nf * 16 + r16];
#pragma unroll
    for (int rr = 0; rr < 4; rr++) {
      const float v = acc[nf][rr] + bv;
      acc[nf][rr] = v;
      rs[rr] += v; rq[rr] += v * v;
    }
  }
#pragma unroll
  for (int off = 1; off < 16; off <<= 1) {
#pragma unroll
    for (int rr = 0; rr < 4; rr++) {
      rs[rr] += __shfl_xor(rs[rr], off);
      rq[rr] += __shfl_xor(rq[rr], off);
    }
  }
  float mu[4], ri[4];
#pragma unroll
  for (int rr = 0; rr < 4; rr++) {
    mu[rr] = rs[rr] * (1.0f / 256.0f);
    const float var = rq[rr] * (1.0f / 256.0f) - mu[rr] * mu[rr];
    ri[rr] = rsqrtf(var + 1e-5f);
  }
#pragma unroll
  for (int nf = 0; nf < 16; nf++) {
    const int col = nf * 16 + r16;
    const float g = ln_g[col], b = ln_b[col];
#pragma unroll
    for (int rr = 0; rr < 4; rr++) {
      const int row = m0 + wm + q * 4 + rr;
      a1[(size_t)row * 256 + col] = (f16)((acc[nf][rr] - mu[rr]) * ri[rr] * g + b);
    }
  }
}

// ============================================================================
// Heads GEMM + energy. Grid TRANSPOSED: (128 m-blocks, 4 speakers).
// ============================================================================
__global__ __launch_bounds__(256) void heads_energy_kernel(
    const f16* __restrict__ A, const f16* __restrict__ Wt,
    const float* __restrict__ bias, float* __restrict__ specs,
    float* __restrict__ energy)
{
  __shared__ __align__(16) f16 As[64 * 256];   // 32 KB
  __shared__ __align__(16) f16 Bs[80 * 256];   // 40 KB
  const int tid = threadIdx.x;
  const int s = blockIdx.y;
  const int m0 = blockIdx.x * 64;
  const int wave = tid >> 6, lane = tid & 63;
  const int q = lane >> 4, r16 = lane & 15;
#pragma unroll
  for (int c = tid; c < 2048; c += 256) {
    const int row = c >> 5, g = c & 31;
    *(f16x8*)((char*)As + row * 512 + ((g ^ (row & 7)) * 16)) =
        *(const f16x8*)(A + (size_t)(m0 + row) * 256 + g * 8);
  }
#pragma unroll
  for (int c = tid; c < 2560; c += 256) {
    const int row = c >> 5, g = c & 31;
    *(f16x8*)((char*)Bs + row * 512 + ((g ^ (row & 7)) * 16)) =
        *(const f16x8*)(Wt + (size_t)(s * 80 + row) * 256 + g * 8);
  }
  __syncthreads();
  const int wm = wave * 16;
  f32x4 acc[5];
#pragma unroll
  for (int nf = 0; nf < 5; nf++) acc[nf] = (f32x4)0.f;
#pragma unroll
  for (int kf = 0; kf < 8; kf++) {
    const int kg = kf * 4 + q;
    const int ar = wm + r16;
    const f16x8 af = *(const f16x8*)((char*)As + ar * 512 + ((kg ^ (ar & 7)) * 16));
#pragma unroll
    for (int nf = 0; nf < 5; nf++) {
      const int br = nf * 16 + r16;
      const f16x8 bf = *(const f16x8*)((char*)Bs + br * 512 + ((kg ^ (br & 7)) * 16));
      acc[nf] = __builtin_amdgcn_mfma_f32_16x16x32_f16(af, bf, acc[nf], 0, 0, 0);
    }
  }
  float bv[5];
#pragma unroll
  for (int nf = 0; nf < 5; nf++) bv[nf] = bias[s * 80 + nf * 16 + r16];
  float rs[4] = {0.f, 0.f, 0.f, 0.f};
#pragma unroll
  for (int rr = 0; rr < 4; rr++) {
    const int row = m0 + wm + q * 4 + rr;
    const int b_ = row >> 10, t_ = row & 1023;
    float* dst = specs + ((size_t)((b_ * 4 + s) * 1024 + t_)) * 80;
#pragma unroll
    for (int nf = 0; nf < 5; nf++) {
      const float v = acc[nf][rr] + bv[nf];
      rs[rr] += v;
      dst[nf * 16 + r16] = v;
    }
  }
#pragma unroll
  for (int off = 1; off < 16; off <<= 1) {
#pragma unroll
    for (int rr = 0; rr < 4; rr++) rs[rr] += __shfl_xor(rs[rr], off);
  }
  if (r16 == 0) {
#pragma unroll
    for (int rr = 0; rr < 4; rr++) {
      const int row = m0 + wm + q * 4 + rr;
      const int b_ = row >> 10, t_ = row & 1023;
      energy[((b_ * 4 + s) << 10) + t_] = rs[rr];
    }
  }
}

// ============================================================================
// Waveforms final: out[n] = noise[n] * (0.5*interp(energy) + 0.5).
// Pure memory-bound now (noise precomputed in prep dispatch).
// + speaker-logits tail block.
// ============================================================================
__global__ __launch_bounds__(256) void waveform_kernel(
    const float* __restrict__ noise, const float* __restrict__ energy,
    float* __restrict__ out, const float* __restrict__ colsum,
    const float* __restrict__ w_spk, const float* __restrict__ b_spk,
    float* __restrict__ logits)
{
  if (blockIdx.x == 5120) {
    const int idx = threadIdx.x;
    if (idx < 32) {
      const int b = idx >> 2, s = idx & 3;
      const float* cs = colsum + b * 256;
      float acc = 0.f;
#pragma unroll 8
      for (int d = 0; d < 256; d++)
        acc = fmaf(cs[d] * (1.0f / 1024.0f), w_spk[d * 4 + s], acc);
      logits[b * 4 + s] = acc + b_spk[s];
    }
    return;
  }
  const unsigned base = (blockIdx.x * 256 + threadIdx.x) * 4;  // [0, 5242880)
  const unsigned i0 = base % 163840u;   // all 4 elems share a row
  const unsigned bs = base / 163840u;
  const float* e = energy + (size_t)bs * 1024;
  const float4 nz = *(const float4*)(noise + base);
  float4 o;
#pragma unroll
  for (int j = 0; j < 4; j++) {
    float pos = ((float)(i0 + j) + 0.5f) * 0.00625f - 0.5f;
    pos = fminf(fmaxf(pos, 0.0f), 1023.0f);
    const int lo = (int)floorf(pos);
    int hi = lo + 1; if (hi > 1023) hi = 1023;
    const float w = pos - (float)lo;
    const float ev = e[lo] * (1.0f - w) + e[hi] * w;
    ((float*)&o)[j] = ((const float*)&nz)[j] * fmaf(ev, 0.5f, 0.5f);
  }
  *(float4*)(out + base) = o;
}

// ============================================================================
extern "C" void kernel_launch(void* const* d_in, const int* in_sizes, int n_in,
                              void* d_out, int out_size, void* d_ws, size_t ws_size,
                              hipStream_t stream)
{
  (void)in_sizes; (void)n_in; (void)out_size; (void)ws_size;
  const float* audio   = (const float*)d_in[0];
  const float* video   = (const float*)d_in[1];
  const float* w_ae    = (const float*)d_in[2];
  const float* b_ae    = (const float*)d_in[3];
  const float* ln_g    = (const float*)d_in[4];
  const float* ln_b    = (const float*)d_in[5];
  const float* w_a1    = (const float*)d_in[6];
  const float* b_a1    = (const float*)d_in[7];
  const float* w_a2    = (const float*)d_in[8];
  const float* b_a2    = (const float*)d_in[9];
  const float* conv_w  = (const float*)d_in[10];
  const float* conv_b  = (const float*)d_in[11];
  const float* w_vfc   = (const float*)d_in[12];
  const float* b_vfc   = (const float*)d_in[13];
  const float* w_f1    = (const float*)d_in[14];
  const float* b_f1    = (const float*)d_in[15];
  const float* w_f2    = (const float*)d_in[16];
  const float* b_f2    = (const float*)d_in[17];
  const float* heads_w = (const float*)d_in[18];
  const float* heads_b = (const float*)d_in[19];
  const float* w_spk   = (const float*)d_in[20];
  const float* b_spk   = (const float*)d_in[21];

  float* ws = (float*)d_ws;
  float* colsum = ws + 2097152;       // 2,048
  float* Sg     = ws + 2099200;       // 37,632
  float* v256   = ws + 2136832;       // 65,536
  float* energy = ws + 2202368;       // 32,768
  float* bp     = ws + 2235136;       // 320  (+pad to 2235456)
  f16* fh = (f16*)(ws + 2235456);
  f16* a1     = fh;                   // 2,097,152 f16
  f16* h16    = a1 + 2097152;         // 4,194,304
  f16* fbuf16 = h16 + 4194304;        // 4,194,304
  f16* a_h    = fbuf16 + 4194304;     // (retired)
  f16* wae_t  = a_h + 1048576;        //    32,768
  f16* wa1_t  = wae_t + 32768;        //   131,072
  f16* wa2_t  = wa1_t + 131072;       //   131,072
  f16* wf1_t  = wa2_t + 131072;       //   262,144
  f16* wf2_t  = wf1_t + 262144;       //   131,072
  f16* wh_t   = wf2_t + 131072;       //    81,920
  float* noise = ws + 16777216;       // 20,971,520 f32 (64MB offset, 84MB)

  float* out_wave   = (float*)d_out;           // 5,242,880
  float* out_specs  = out_wave + 5242880;      // 2,621,440
  float* out_logits = out_specs + 2621440;     // 32

  // 1. video tap-reduce + weight transposes + colsum zero + NOISE GEN
  prep_video_kernel<<<8906, 256, 0, stream>>>(video, Sg, w_ae, w_a1, w_a2,
                                              w_f1, w_f2, heads_w, heads_b,
                                              wae_t, wa1_t, wa2_t, wf1_t,
                                              wf2_t, wh_t, bp, colsum, noise);
  // 2. vpool+FC  ||  ae GEMM + bias + LayerNorm -> a1 (f16)
  vpool_aeln_kernel<<<384, 256, 0, stream>>>(Sg, conv_w, conv_b, w_vfc, b_vfc,
                                             v256, audio, wae_t, b_ae,
                                             ln_g, ln_b, a1);
  // 3. a1 MLP up: relu(a1 @ w_a1)   [grid: x=M/128, y=N/64]
  hgemm<128, 1, 1><<<dim3(64, 8), 256, 0, stream>>>(a1, wa1_t, b_a1, h16, 512, 0, 512, 256, nullptr);
  // 4. a2 MLP down -> fbuf cols [0,256)  +  video interp (y==4) -> cols [256,512)
  hgemm<64, 0, 1, 1><<<dim3(128, 5), 256, 0, stream>>>(h16, wa2_t, b_a2, fbuf16, 512, 0, 256, 512, v256);
  // 5. fusion up: relu(fbuf @ w_f1)
  hgemm<128, 1, 1><<<dim3(64, 8), 256, 0, stream>>>(fbuf16, wf1_t, b_f1, h16, 512, 0, 512, 512, nullptr);
  // 6. fusion down -> a1 (f16) + colsum atomics
  hgemm<64, 0, 2><<<dim3(128, 4), 256, 0, stream>>>(h16, wf2_t, b_f2, a1, 256, 0, 256, 512, colsum);
  // 7. heads -> specs [B,S,T,80] + energy row-sums  [grid: x=M/64, y=speaker]
  heads_energy_kernel<<<dim3(128, 4), 256, 0, stream>>>(a1, wh_t, bp, out_specs, energy);
  // 8. waveforms (noise * energy-interp) + speaker logits (tail block)
  waveform_kernel<<<5121, 256, 0, stream>>>(noise, energy, out_wave, colsum,
                                            w_spk, b_spk, out_logits);
}